// Round 15
// baseline (208.409 us; speedup 1.0000x reference)
//
#include <hip/hip_runtime.h>
#include <hip/hip_bf16.h>
#include <cstdint>
#include <cstddef>

#define N_NODES 8192
#define E_RAW   131072
#define E_TOT   (E_RAW + N_NODES)   // 139264
#define HEADS   4

typedef __attribute__((ext_vector_type(8))) __bf16 bf16x8;
typedef __attribute__((ext_vector_type(4))) float f32x4;
typedef __attribute__((ext_vector_type(2))) float f32x2;

__device__ __forceinline__ void gload_lds16(const void* g, void* lds) {
  __builtin_amdgcn_global_load_lds(
      (const __attribute__((address_space(1))) unsigned int*)g,
      (__attribute__((address_space(3))) unsigned int*)lds, 16, 0, 0);
}

__device__ __forceinline__ float bfbits2f(unsigned short u) {
  return __uint_as_float((unsigned)u << 16);
}
__device__ __forceinline__ unsigned short f2bfbits(float f) {
  __hip_bfloat16 b = __float2bfloat16(f);
  return *(unsigned short*)&b;
}
__device__ __forceinline__ f32x2 unpk2(unsigned u) {
  return (f32x2){__uint_as_float(u << 16), __uint_as_float(u & 0xffff0000u)};
}
__device__ __forceinline__ unsigned char f32_to_fp8(float v) {
  int r = __builtin_amdgcn_cvt_pk_fp8_f32(v, v, 0, false);
  return (unsigned char)(r & 0xff);
}

__device__ __forceinline__ int eSrc(const int* __restrict__ src, int e) {
  return (e < E_RAW) ? src[e] : (e - E_RAW);
}
__device__ __forceinline__ int eDst(const int* __restrict__ dst, int e) {
  return (e < E_RAW) ? dst[e] : (e - E_RAW);
}

// ---------------- fused prep ----------------
// [0,8192) build_x | [8192,9216) cvt h | [9216,9472) ea partials
// [9472,9537) zero ICNT/IPOS/DPOS | [9537,9550) biases

__global__ __launch_bounds__(256) void prep_kernel(
    const float* __restrict__ ct, const float* __restrict__ cs,
    const float* __restrict__ ep, const float* __restrict__ fl,
    const float* __restrict__ h, const float* __restrict__ ea,
    const float* bl1, const float* br1, const float* bl2, const float* br2,
    const float* rb1, const float* wb1, const float* pb1, const float* db1,
    __hip_bfloat16* __restrict__ x, __hip_bfloat16* __restrict__ Hb,
    float* __restrict__ MP, int* __restrict__ zero_region,
    float* B1, float* B2, float* BH) {
  __shared__ float sm[256];
  int blk = blockIdx.x;
  int tid = threadIdx.x;
  if (blk < 8192) {
    int i = blk;
    for (int j = tid; j < 832; j += 256) {
      float v;
      if (j < 256)      v = ct[(size_t)i * 256 + j];
      else if (j < 512) v = cs[(size_t)i * 256 + (j - 256)];
      else if (j < 514) v = ep[(size_t)i * 2 + (j - 512)];
      else if (j < 770) v = fl[(size_t)i * 256 + (j - 514)];
      else              v = 0.f;
      x[(size_t)i * 832 + j] = __float2bfloat16(v);
    }
  } else if (blk < 9216) {
    size_t base = ((size_t)(blk - 8192) * 256 + tid) * 8;
    float4 a = *(const float4*)(h + base);
    float4 b = *(const float4*)(h + base + 4);
    unsigned short o[8];
    o[0]=f2bfbits(a.x); o[1]=f2bfbits(a.y); o[2]=f2bfbits(a.z); o[3]=f2bfbits(a.w);
    o[4]=f2bfbits(b.x); o[5]=f2bfbits(b.y); o[6]=f2bfbits(b.z); o[7]=f2bfbits(b.w);
    *(uint4*)((unsigned short*)Hb + base) = *(uint4*)o;
  } else if (blk < 9472) {
    int bb = blk - 9216;
    float acc = 0.f;
    for (int i = bb * 256 + tid; i < E_RAW; i += 256 * 256) acc += ea[i];
    sm[tid] = acc; __syncthreads();
    for (int s = 128; s; s >>= 1) { if (tid < s) sm[tid] += sm[tid + s]; __syncthreads(); }
    if (tid == 0) MP[bb] = sm[0];
  } else if (blk < 9537) {
    int i = (blk - 9472) * 256 + tid;
    if (i < 2 * N_NODES + 64) zero_region[i] = 0;
  } else {
    int i = (blk - 9537) * 256 + tid;
    if (i < 512) B1[i] = (i < 256) ? bl1[i] : br1[i - 256];
    else if (i < 2560) { int k = i - 512; B2[k] = (k < 1024) ? bl2[k] : br2[k - 1024]; }
    else if (i < 3328) {
      int k = i - 2560;
      BH[k] = (k < 256) ? rb1[k] : (k < 512) ? wb1[k - 256] : (k < 640) ? pb1[k - 512] : db1[k - 640];
    }
  }
}

// ---------------- all weight transposes ----------------

__global__ __launch_bounds__(256) void wt_all(
    const float* w0, const float* w1, const float* w2, const float* w3,
    const float* w4, const float* w5, const float* w6, const float* w7,
    const float* w8, const float* w9,
    __hip_bfloat16* WT1, __hip_bfloat16* WT2, __hip_bfloat16* WTih,
    __hip_bfloat16* WThh, __hip_bfloat16* WTh) {
  const int cum[10] = {208, 416, 672, 928, 1120, 1312, 1376, 1440, 1472, 1504};
  const int Kt[10]  = {770, 770, 256, 256, 256, 256, 256, 256, 256, 256};
  const int Nt[10]  = {256, 256, 1024, 1024, 768, 768, 256, 256, 128, 128};
  const int KPt[10] = {832, 832, 256, 256, 256, 256, 256, 256, 256, 256};
  const int n0t[10] = {0, 256, 0, 1024, 0, 0, 0, 256, 512, 640};
  int job = 0;
  while (blockIdx.x >= (unsigned)cum[job]) ++job;
  int lb = blockIdx.x - (job ? cum[job - 1] : 0);
  int K = Kt[job], N = Nt[job], KP = KPt[job], n0 = n0t[job];
  int tilesX = KP >> 5;
  int k0 = (lb % tilesX) * 32, nb = (lb / tilesX) * 32;
  const float* W;
  switch (job) {
    case 0: W = w0; break; case 1: W = w1; break; case 2: W = w2; break;
    case 3: W = w3; break; case 4: W = w4; break; case 5: W = w5; break;
    case 6: W = w6; break; case 7: W = w7; break; case 8: W = w8; break;
    default: W = w9; break;
  }
  __hip_bfloat16* WT = (job < 2) ? WT1 : (job < 4) ? WT2 : (job == 4) ? WTih
                       : (job == 5) ? WThh : WTh;
  __shared__ float sm[32][33];
  int tx = threadIdx.x & 31, ty = threadIdx.x >> 5;
  for (int yy = ty; yy < 32; yy += 8) {
    int k = k0 + yy, n = nb + tx;
    sm[yy][tx] = (k < K && n < N) ? W[(size_t)k * N + n] : 0.f;
  }
  __syncthreads();
  for (int yy = ty; yy < 32; yy += 8) {
    int n = nb + yy, k = k0 + tx;
    if (n < N) WT[(size_t)(n0 + n) * KP + k] = __float2bfloat16(sm[tx][yy]);
  }
}

// ---------------- CSR build ----------------

__global__ void csr_count(const int* __restrict__ dst, int* __restrict__ cnt) {
  int e = blockIdx.x * blockDim.x + threadIdx.x;
  if (e < E_TOT) atomicAdd(&cnt[eDst(dst, e)], 1);
}

__global__ __launch_bounds__(1024) void csr_scan(const int* __restrict__ cnt,
                                                 int* __restrict__ off,
                                                 float* __restrict__ MP,
                                                 int* __restrict__ doff) {
  __shared__ int part[1024];
  __shared__ float sm[256];
  __shared__ int hist[64];
  int t = threadIdx.x;
  if (t < 256) sm[t] = MP[t];
  if (t < 64) hist[t] = 0;
  __syncthreads();
  for (int s = 128; s; s >>= 1) { if (t < s) sm[t] += sm[t + s]; __syncthreads(); }
  if (t == 0) MP[256] = sm[0] * (1.f / (float)E_RAW);
  int base = t * 8;
  int loc[8];
  int acc8 = 0;
#pragma unroll
  for (int i = 0; i < 8; ++i) {
    int c = cnt[base + i];
    loc[i] = acc8; acc8 += c;
    atomicAdd(&hist[min(c, 63)], 1);
  }
  part[t] = acc8; __syncthreads();
  for (int d = 1; d < 1024; d <<= 1) {
    int v = (t >= d) ? part[t - d] : 0;
    __syncthreads();
    part[t] += v;
    __syncthreads();
  }
  int pre = (t == 0) ? 0 : part[t - 1];
#pragma unroll
  for (int i = 0; i < 8; ++i) off[base + i] = pre + loc[i];
  if (t == 1023) off[8192] = part[1023];
  __syncthreads();
  if (t == 0) {
    int acc = 0;
    for (int bb = 63; bb >= 0; --bb) { doff[bb] = acc; acc += hist[bb]; }
  }
}

__global__ void csr_fill(const int* __restrict__ src, const int* __restrict__ dst,
                         const float* __restrict__ ea, const float* __restrict__ eamean,
                         const int* __restrict__ off, int* __restrict__ pos,
                         int* __restrict__ srcn, float* __restrict__ eav,
                         const int* __restrict__ cnt, const int* __restrict__ doff,
                         int* __restrict__ dpos, int* __restrict__ perm) {
  int blk = blockIdx.x;
  if (blk < 544) {
    int e = blk * 256 + threadIdx.x;
    if (e >= E_TOT) return;
    int d = eDst(dst, e);
    int p = off[d] + atomicAdd(&pos[d], 1);
    srcn[p] = eSrc(src, e);
    eav[p] = (e < E_RAW) ? ea[e] : eamean[0];
  } else {
    int i = (blk - 544) * 256 + threadIdx.x;
    if (i >= N_NODES) return;
    int bin = min(cnt[i], 63);
    int p = doff[bin] + atomicAdd(&dpos[bin], 1);
    perm[p] = i;
  }
}

// ---------------- bf16 MFMA GEMM (128x128 tile, 8 waves of 32x64, BK=64, swizzled LDS) ----------------
// OUT: 0 bf16 all | 3 bf16 relu all
//      6 conv1: fp8 (cols<256) + bf16 cols>=256 | 7 conv2: fp8 (cols<1024) + bf16 cols>=1024

template <int OUT>
__global__ __launch_bounds__(512) void mfma_gemm(
    const __hip_bfloat16* __restrict__ A, const __hip_bfloat16* __restrict__ BT,
    const float* __restrict__ bias, void* __restrict__ Cout, int KP, int N,
    unsigned char* __restrict__ Cfp8) {
  __shared__ uint4 AsBuf[1024];
  __shared__ uint4 BsBuf[1024];
  char* Asc = (char*)AsBuf;
  char* Bsc = (char*)BsBuf;
  int tid = threadIdx.x;
  int lane = tid & 63;
  int wid = tid >> 6;
  int wr = wid >> 1;
  int wc = wid & 1;
  int bm = blockIdx.y * 128;
  int bn = blockIdx.x * 128;
  f32x4 acc[2][4];
#pragma unroll
  for (int i = 0; i < 2; ++i)
#pragma unroll
    for (int j = 0; j < 4; ++j) acc[i][j] = (f32x4){0.f, 0.f, 0.f, 0.f};

  int nK = KP >> 6;
  for (int kt = 0; kt < nK; ++kt) {
    int k0 = kt * 64;
#pragma unroll
    for (int i = 0; i < 2; ++i) {
      int p = i * 512 + tid;
      int row = p >> 3, cc = p & 7;
      int sc = cc ^ (row & 7);
      gload_lds16(A + (size_t)(bm + row) * KP + k0 + sc * 8, Asc + p * 16);
      gload_lds16(BT + (size_t)(bn + row) * KP + k0 + sc * 8, Bsc + p * 16);
    }
    __syncthreads();
#pragma unroll
    for (int s = 0; s < 2; ++s) {
      bf16x8 af[2], bfr[4];
#pragma unroll
      for (int f = 0; f < 2; ++f) {
        int r = wr * 32 + f * 16 + (lane & 15);
        int ch = (s * 4 + (lane >> 4)) ^ (r & 7);
        af[f] = *(const bf16x8*)(Asc + r * 128 + ch * 16);
      }
#pragma unroll
      for (int f = 0; f < 4; ++f) {
        int n = wc * 64 + f * 16 + (lane & 15);
        int cb = (s * 4 + (lane >> 4)) ^ (n & 7);
        bfr[f] = *(const bf16x8*)(Bsc + n * 128 + cb * 16);
      }
#pragma unroll
      for (int fm = 0; fm < 2; ++fm)
#pragma unroll
        for (int fn = 0; fn < 4; ++fn)
          acc[fm][fn] = __builtin_amdgcn_mfma_f32_16x16x32_bf16(af[fm], bfr[fn], acc[fm][fn], 0, 0, 0);
    }
    __syncthreads();
  }
  int rbase = bm + wr * 32 + (lane >> 4) * 4;
  int cbase = bn + wc * 64 + (lane & 15);
#pragma unroll
  for (int fm = 0; fm < 2; ++fm)
#pragma unroll
    for (int fn = 0; fn < 4; ++fn) {
      int col = cbase + fn * 16;
      float bv = bias[col];
#pragma unroll
      for (int j = 0; j < 4; ++j) {
        int row = rbase + fm * 16 + j;
        float v = acc[fm][fn][j] + bv;
        if (OUT == 3) v = fmaxf(v, 0.f);
        if (OUT == 0 || OUT == 3)
          ((__hip_bfloat16*)Cout)[(size_t)row * N + col] = __float2bfloat16(v);
        if (OUT == 6) {
          if (col < 256) Cfp8[(size_t)row * 256 + col] = f32_to_fp8(v);
          else ((__hip_bfloat16*)Cout)[(size_t)row * N + col] = __float2bfloat16(v);
        }
        if (OUT == 7) {
          if (col < 1024) Cfp8[(size_t)row * 1024 + col] = f32_to_fp8(v);
          else ((__hip_bfloat16*)Cout)[(size_t)row * N + col] = __float2bfloat16(v);
        }
      }
    }
}

// ---------------- fused GATv2 conv1: 1 wave/node (LPT order), fp8 gathers ----------------

__global__ __launch_bounds__(256) void gat_fused1(
    const unsigned char* __restrict__ XL8,   // [n][256] fp8 xl
    const __hip_bfloat16* __restrict__ XLR,  // [n][512] (xr half at +256)
    const int* __restrict__ off, const int* __restrict__ srcn,
    const float* __restrict__ eav, const int* __restrict__ perm,
    const float* __restrict__ We, const float* __restrict__ att,
    const float* __restrict__ bias, __hip_bfloat16* __restrict__ X1) {
  int d = perm[(blockIdx.x * 256 + threadIdx.x) >> 6];
  int lane = threadIdx.x & 63;
  int q = lane & 15;
  int j0 = (lane >> 4) * 64 + q * 4;
  const unsigned short* X = (const unsigned short*)XLR;
  uint2 xv = *(const uint2*)(X + (size_t)d * 512 + 256 + j0);
  f32x2 xr[2] = {unpk2(xv.x), unpk2(xv.y)};
  f32x2 we[2] = {*(const f32x2*)(We + j0), *(const f32x2*)(We + j0 + 2)};
  f32x2 at[2] = {*(const f32x2*)(att + j0), *(const f32x2*)(att + j0 + 2)};
  int b = off[d], e1 = off[d + 1], pe = e1 - 1;
  int sB = srcn[b]; float eaA = eav[b];
  unsigned rA = *(const unsigned*)(XL8 + (size_t)sB * 256 + j0);
  int p1 = min(b + 1, pe); sB = srcn[p1]; float eaB = eav[p1];
  float m = -INFINITY, ss = 0.f;
  f32x2 a[2] = {(f32x2){0.f, 0.f}, (f32x2){0.f, 0.f}};
  for (int p = b; p < e1; ++p) {
    unsigned cc = rA; float ea = eaA; eaA = eaB;
    rA = *(const unsigned*)(XL8 + (size_t)sB * 256 + j0);
    int p2 = min(p + 2, pe); sB = srcn[p2]; eaB = eav[p2];
    f32x2 v[2];
    v[0] = (f32x2){__builtin_amdgcn_cvt_f32_fp8(cc, 0), __builtin_amdgcn_cvt_f32_fp8(cc, 1)};
    v[1] = (f32x2){__builtin_amdgcn_cvt_f32_fp8(cc, 2), __builtin_amdgcn_cvt_f32_fp8(cc, 3)};
    f32x2 ea2 = (f32x2){ea, ea};
    f32x2 t2 = (f32x2){0.f, 0.f};
#pragma unroll
    for (int i = 0; i < 2; ++i) {
      f32x2 gg = (v[i] + xr[i]) + ea2 * we[i];
      f32x2 lr = __builtin_elementwise_max(gg, 0.2f * gg);
      t2 = t2 + lr * at[i];
    }
    float t = t2.x + t2.y;
    t += __shfl_xor(t, 8, 64); t += __shfl_xor(t, 4, 64);
    t += __shfl_xor(t, 2, 64); t += __shfl_xor(t, 1, 64);
    if (__all(t <= m)) {
      float wp = __expf(t - m);
      ss += wp;
      f32x2 wp2 = (f32x2){wp, wp};
#pragma unroll
      for (int i = 0; i < 2; ++i) a[i] = a[i] + wp2 * v[i];
    } else {
      float mn = fmaxf(m, t);
      float scl = __expf(m - mn);
      float wp = __expf(t - mn);
      ss = fmaf(ss, scl, wp);
      f32x2 wp2 = (f32x2){wp, wp}, s2 = (f32x2){scl, scl};
#pragma unroll
      for (int i = 0; i < 2; ++i) a[i] = a[i] * s2 + wp2 * v[i];
      m = mn;
    }
  }
  float inv = 1.f / (ss + 1e-16f);
  unsigned short o[4];
  o[0] = f2bfbits(fmaxf(fmaf(a[0].x, inv, bias[j0]), 0.f));
  o[1] = f2bfbits(fmaxf(fmaf(a[0].y, inv, bias[j0 + 1]), 0.f));
  o[2] = f2bfbits(fmaxf(fmaf(a[1].x, inv, bias[j0 + 2]), 0.f));
  o[3] = f2bfbits(fmaxf(fmaf(a[1].y, inv, bias[j0 + 3]), 0.f));
  *(uint2*)((unsigned short*)X1 + (size_t)d * 256 + j0) = *(uint2*)o;
}

// ---------------- fused GATv2 conv2: 1 wave/node (LPT order), fp8 gathers, head-mean ----------------

__global__ __launch_bounds__(256) void gat_fused2(
    const unsigned char* __restrict__ XL8,   // [n][1024] fp8 e4m3
    const __hip_bfloat16* __restrict__ XLR,  // [n][2048] (xr half at +1024)
    const int* __restrict__ off, const int* __restrict__ srcn,
    const float* __restrict__ eav, const int* __restrict__ perm,
    const float* __restrict__ We, const float* __restrict__ att,
    const float* __restrict__ bias, __hip_bfloat16* __restrict__ X2) {
  int d = perm[(blockIdx.x * 256 + threadIdx.x) >> 6];
  int lane = threadIdx.x & 63;
  int g = lane >> 4, q = lane & 15;
  int j0 = g * 256 + q * 16;
  const unsigned short* X = (const unsigned short*)XLR;
  f32x2 xr[8], we[8], at[8], a[8];
  {
    const uint4* xp = (const uint4*)(X + (size_t)d * 2048 + 1024 + j0);
    uint4 r0 = xp[0], r1 = xp[1];
    xr[0] = unpk2(r0.x); xr[1] = unpk2(r0.y); xr[2] = unpk2(r0.z); xr[3] = unpk2(r0.w);
    xr[4] = unpk2(r1.x); xr[5] = unpk2(r1.y); xr[6] = unpk2(r1.z); xr[7] = unpk2(r1.w);
#pragma unroll
    for (int i = 0; i < 8; ++i) {
      we[i] = *(const f32x2*)(We + j0 + 2 * i);
      at[i] = *(const f32x2*)(att + j0 + 2 * i);
      a[i] = (f32x2){0.f, 0.f};
    }
  }
  int b = off[d], e1 = off[d + 1], pe = e1 - 1;
  int sB = srcn[b]; float eaA = eav[b];
  uint4 rA = *(const uint4*)(XL8 + (size_t)sB * 1024 + j0);
  int p1 = min(b + 1, pe); sB = srcn[p1]; float eaB = eav[p1];
  float m = -INFINITY, ss = 0.f;
  for (int p = b; p < e1; ++p) {
    uint4 cc = rA; float ea = eaA; eaA = eaB;
    rA = *(const uint4*)(XL8 + (size_t)sB * 1024 + j0);
    int p2 = min(p + 2, pe); sB = srcn[p2]; eaB = eav[p2];
    f32x2 v[8];
    v[0] = (f32x2){__builtin_amdgcn_cvt_f32_fp8(cc.x, 0), __builtin_amdgcn_cvt_f32_fp8(cc.x, 1)};
    v[1] = (f32x2){__builtin_amdgcn_cvt_f32_fp8(cc.x, 2), __builtin_amdgcn_cvt_f32_fp8(cc.x, 3)};
    v[2] = (f32x2){__builtin_amdgcn_cvt_f32_fp8(cc.y, 0), __builtin_amdgcn_cvt_f32_fp8(cc.y, 1)};
    v[3] = (f32x2){__builtin_amdgcn_cvt_f32_fp8(cc.y, 2), __builtin_amdgcn_cvt_f32_fp8(cc.y, 3)};
    v[4] = (f32x2){__builtin_amdgcn_cvt_f32_fp8(cc.z, 0), __builtin_amdgcn_cvt_f32_fp8(cc.z, 1)};
    v[5] = (f32x2){__builtin_amdgcn_cvt_f32_fp8(cc.z, 2), __builtin_amdgcn_cvt_f32_fp8(cc.z, 3)};
    v[6] = (f32x2){__builtin_amdgcn_cvt_f32_fp8(cc.w, 0), __builtin_amdgcn_cvt_f32_fp8(cc.w, 1)};
    v[7] = (f32x2){__builtin_amdgcn_cvt_f32_fp8(cc.w, 2), __builtin_amdgcn_cvt_f32_fp8(cc.w, 3)};
    f32x2 ea2 = (f32x2){ea, ea};
    f32x2 t2 = (f32x2){0.f, 0.f};
#pragma unroll
    for (int i = 0; i < 8; ++i) {
      f32x2 gg = (v[i] + xr[i]) + ea2 * we[i];
      f32x2 lr = __builtin_elementwise_max(gg, 0.2f * gg);
      t2 = t2 + lr * at[i];
    }
    float t = t2.x + t2.y;
    t += __shfl_xor(t, 8, 64); t += __shfl_xor(t, 4, 64);
    t += __shfl_xor(t, 2, 64); t += __shfl_xor(t, 1, 64);
    if (__all(t <= m)) {
      float wp = __expf(t - m);
      ss += wp;
      f32x2 wp2 = (f32x2){wp, wp};
#pragma unroll
      for (int i = 0; i < 8; ++i) a[i] = a[i] + wp2 * v[i];
    } else {
      float mn = fmaxf(m, t);
      float scl = __expf(m - mn);
      float wp = __expf(t - mn);
      ss = fmaf(ss, scl, wp);
      f32x2 wp2 = (f32x2){wp, wp}, s2 = (f32x2){scl, scl};
#pragma unroll
      for (int i = 0; i < 8; ++i) a[i] = a[i] * s2 + wp2 * v[i];
      m = mn;
    }
  }
  float inv = 1.f / (ss + 1e-16f);
  f32x2 inv2 = (f32x2){inv, inv};
#pragma unroll
  for (int i = 0; i < 8; ++i) {
    f32x2 r2 = a[i] * inv2;
    r2.x += __shfl_xor(r2.x, 16, 64);
    r2.x += __shfl_xor(r2.x, 32, 64);
    r2.y += __shfl_xor(r2.y, 16, 64);
    r2.y += __shfl_xor(r2.y, 32, 64);
    a[i] = r2;
  }
  if (g == 0) {
    unsigned short o[16];
#pragma unroll
    for (int i = 0; i < 8; ++i) {
      o[2 * i]     = f2bfbits(fmaf(0.25f, a[i].x, bias[q * 16 + 2 * i]));
      o[2 * i + 1] = f2bfbits(fmaf(0.25f, a[i].y, bias[q * 16 + 2 * i + 1]));
    }
    uint4* op = (uint4*)((unsigned short*)X2 + (size_t)d * 256 + q * 16);
    op[0] = ((uint4*)o)[0];
    op[1] = ((uint4*)o)[1];
  }
}

// ---------------- fused GRU GEMM: 32x128 tiles, 256 thr (4 waves of 16x64), grid (2,256) ----------------

__global__ __launch_bounds__(256) void gru_gemm(
    const __hip_bfloat16* __restrict__ X2b,  // [8192][256]
    const __hip_bfloat16* __restrict__ Hb,   // [8192][256]
    const __hip_bfloat16* __restrict__ WTih, // [768][256]
    const __hip_bfloat16* __restrict__ WThh, // [768][256]
    const float* __restrict__ bih, const float* __restrict__ bhh,
    const float* __restrict__ hf,
    float* __restrict__ hn, __hip_bfloat16* __restrict__ hnb) {
  __shared__ uint4 AxB[256];   // 4KB: 32 rows x 64 k
  __shared__ uint4 AhB[256];
  __shared__ uint4 BiB[1024];  // 16KB: 128 n x 64 k
  __shared__ uint4 BhB[1024];
  char* Ax = (char*)AxB;
  char* Ah = (char*)AhB;
  char* Bi = (char*)BiB;
  char* Bh = (char*)BhB;
  int tid = threadIdx.x;
  int lane = tid & 63, wid = tid >> 6;   // 4 waves
  int wr = wid >> 1, wc = wid & 1;       // wave tile 16 rows x 64 cols
  int bm = blockIdx.y * 32;
  int c0 = blockIdx.x * 128;
  float rv[16], zv[16];
  float outv[16];
  for (int gate = 0; gate < 3; ++gate) {
    f32x4 ai[4], ah[4];
#pragma unroll
    for (int j = 0; j < 4; ++j) { ai[j] = (f32x4){0.f,0.f,0.f,0.f}; ah[j] = (f32x4){0.f,0.f,0.f,0.f}; }
    for (int kt = 0; kt < 4; ++kt) {
      int k0 = kt * 64;
      {
        int p = tid;                     // 256 chunks: 32 rows x 8
        int row = p >> 3, cc = p & 7;
        int sc = cc ^ (row & 7);
        gload_lds16(X2b + (size_t)(bm + row) * 256 + k0 + sc * 8, Ax + p * 16);
        gload_lds16(Hb + (size_t)(bm + row) * 256 + k0 + sc * 8, Ah + p * 16);
      }
#pragma unroll
      for (int i = 0; i < 4; ++i) {      // 1024 chunks: 128 n x 8
        int p = i * 256 + tid;
        int row = p >> 3, cc = p & 7;
        int sc = cc ^ (row & 7);
        int n = gate * 256 + c0 + row;
        gload_lds16(WTih + (size_t)n * 256 + k0 + sc * 8, Bi + p * 16);
        gload_lds16(WThh + (size_t)n * 256 + k0 + sc * 8, Bh + p * 16);
      }
      __syncthreads();
#pragma unroll
      for (int s = 0; s < 2; ++s) {
        int rl = wr * 16 + (lane & 15);
        int ch = (s * 4 + (lane >> 4)) ^ (rl & 7);
        bf16x8 axf = *(const bf16x8*)(Ax + rl * 128 + ch * 16);
        bf16x8 ahf = *(const bf16x8*)(Ah + rl * 128 + ch * 16);
        bf16x8 bif[4], bhf[4];
#pragma unroll
        for (int f = 0; f < 4; ++f) {
          int nl = wc * 64 + f * 16 + (lane & 15);
          int cb = (s * 4 + (lane >> 4)) ^ (nl & 7);
          bif[f] = *(const bf16x8*)(Bi + nl * 128 + cb * 16);
          bhf[f] = *(const bf16x8*)(Bh + nl * 128 + cb * 16);
        }
#pragma unroll
        for (int fn = 0; fn < 4; ++fn) {
          ai[fn] = __builtin_amdgcn_mfma_f32_16x16x32_bf16(axf, bif[fn], ai[fn], 0, 0, 0);
          ah[fn] = __builtin_amdgcn_mfma_f32_16x16x32_bf16(ahf, bhf[fn], ah[fn], 0, 0, 0);
        }
      }
      __syncthreads();
    }
#pragma unroll
    for (int fn = 0; fn < 4; ++fn) {
      int colL = wc * 64 + fn * 16 + (lane & 15);
      int ng = gate * 256 + c0 + colL;
      float bi_v = bih[ng], bh_v = bhh[ng];
#pragma unroll
      for (int j = 0; j < 4; ++j) {
        int k = fn * 4 + j;
        float vi = ai[fn][j] + bi_v;
        float vh = ah[fn][j] + bh_v;
        if (gate == 0) rv[k] = 1.f / (1.f + __expf(-(vi + vh)));
        else if (gate == 1) zv[k] = 1.f / (1.f + __expf(-(vi + vh)));
        else outv[k] = tanhf(vi + rv[k] * vh);
      }
    }
  }
#pragma unroll
  for (int fn = 0; fn < 4; ++fn) {
    int colL = wc * 64 + fn * 16 + (lane & 15);
    int chn = c0 + colL;
#pragma unroll
    for (int j = 0; j < 4; ++j) {
      int k = fn * 4 + j;
      int row = bm + wr * 16 + (lane >> 4) * 4 + j;
      float h0 = hf[(size_t)row * 256 + chn];
      float v = (1.f - zv[k]) * outv[k] + zv[k] * h0;
      hn[(size_t)row * 256 + chn] = v;
      hnb[(size_t)row * 256 + chn] = __float2bfloat16(v);
    }
  }
}

// ---------------- all 4 final heads (bf16 T input) ----------------

__global__ __launch_bounds__(256) void heads_final(
    const __hip_bfloat16* __restrict__ Tb,
    const float* __restrict__ rW2, const float* __restrict__ rb2,
    const float* __restrict__ wW2, const float* __restrict__ wb2,
    const float* __restrict__ pW2, const float* __restrict__ pb2,
    const float* __restrict__ dW2, const float* __restrict__ db2,
    float* __restrict__ o_res, float* __restrict__ o_w,
    float* __restrict__ AP, float* __restrict__ o_ad) {
  int node = (blockIdx.x * 256 + threadIdx.x) >> 6;
  int lane = threadIdx.x & 63;
  const unsigned short* t = (const unsigned short*)Tb + (size_t)node * 768;
  ushort4 tr = *(const ushort4*)(t + lane * 4);
  ushort4 tw = *(const ushort4*)(t + 256 + lane * 4);
  float trf[4] = {bfbits2f(tr.x), bfbits2f(tr.y), bfbits2f(tr.z), bfbits2f(tr.w)};
  float twf[4] = {bfbits2f(tw.x), bfbits2f(tw.y), bfbits2f(tw.z), bfbits2f(tw.w)};
  float tpf[4] = {0.f, 0.f, 0.f, 0.f}, tdf[4] = {0.f, 0.f, 0.f, 0.f};
  if (lane < 32) {
    ushort4 tp = *(const ushort4*)(t + 512 + lane * 4);
    ushort4 td = *(const ushort4*)(t + 640 + lane * 4);
    tpf[0] = bfbits2f(tp.x); tpf[1] = bfbits2f(tp.y); tpf[2] = bfbits2f(tp.z); tpf[3] = bfbits2f(tp.w);
    tdf[0] = bfbits2f(td.x); tdf[1] = bfbits2f(td.y); tdf[2] = bfbits2f(td.z); tdf[3] = bfbits2f(td.w);
  }
  float r0 = 0.f, r1 = 0.f, w0 = 0.f, w1 = 0.f, pp = 0.f, dd = 0.f;
#pragma unroll
  for (int i = 0; i < 4; ++i) {
    int k = lane * 4 + i;
    r0 = fmaf(trf[i], rW2[k * 2], r0);
    r1 = fmaf(trf[i], rW2[k * 2 + 1], r1);
    w0 = fmaf(twf[i], wW2[k * 2], w0);
    w1 = fmaf(twf[i], wW2[k * 2 + 1], w1);
  }
  if (lane < 32) {
#pragma unroll
    for (int i = 0; i < 4; ++i) {
      int k = lane * 4 + i;
      pp = fmaf(tpf[i], pW2[k], pp);
      dd = fmaf(tdf[i], dW2[k], dd);
    }
  }
#pragma unroll
  for (int o = 32; o; o >>= 1) {
    r0 += __shfl_xor(r0, o, 64); r1 += __shfl_xor(r1, o, 64);
    w0 += __shfl_xor(w0, o, 64); w1 += __shfl_xor(w1, o, 64);
    pp += __shfl_xor(pp, o, 64); dd += __shfl_xor(dd, o, 64);
  }
  if (lane == 0) {
    o_res[(size_t)node * 2]     = r0 + rb2[0];
    o_res[(size_t)node * 2 + 1] = r1 + rb2[1];
    float sw0 = w0 + wb2[0], sw1 = w1 + wb2[1];
    o_w[(size_t)node * 2]     = 1.f / (1.f + __expf(-sw0));
    o_w[(size_t)node * 2 + 1] = 1.f / (1.f + __expf(-sw1));
    float vp = pp + pb2[0];
    AP[node] = fmaxf(vp, 0.f) + log1pf(__expf(-fabsf(vp)));
    float vd = dd + db2[0];
    o_ad[node] = fmaxf(vd, 0.f) + log1pf(__expf(-fabsf(vd)));
  }
}

__global__ void ap_reduce(const float* __restrict__ ap, float* __restrict__ out) {
  __shared__ float sm[256];
  int b = blockIdx.x, tid = threadIdx.x;
  float acc = 0.f;
  for (int i = tid; i < 2048; i += 256) acc += ap[b * 2048 + i];
  sm[tid] = acc; __syncthreads();
  for (int s = 128; s; s >>= 1) { if (tid < s) sm[tid] += sm[tid + s]; __syncthreads(); }
  if (tid == 0) out[b] = sm[0] * (1.f / 2048.f);
}

// ---------------- launch ----------------

extern "C" void kernel_launch(void* const* d_in, const int* in_sizes, int n_in,
                              void* d_out, int out_size, void* d_ws, size_t ws_size,
                              hipStream_t stream) {
  const float* h        = (const float*)d_in[0];
  const float* c_temp   = (const float*)d_in[1];
  const float* c_stereo = (const float*)d_in[2];
  const float* e_proj   = (const float*)d_in[3];
  const float* f_Lt     = (const float*)d_in[4];
  const int*   edges    = (const int*)d_in[5];
  const float* eattr    = (const float*)d_in[6];
  const float* Wl1 = (const float*)d_in[7];  const float* bl1 = (const float*)d_in[8];
  const float* Wr1 = (const float*)d_in[9];  const float* br1 = (const float*)d_in[10];
  const float* We1 = (const float*)d_in[11]; const float* att1 = (const float*)d_in[12];
  const float* bias1 = (const float*)d_in[13];
  const float* Wl2 = (const float*)d_in[14]; const float* bl2 = (const float*)d_in[15];
  const float* Wr2 = (const float*)d_in[16]; const float* br2 = (const float*)d_in[17];
  const float* We2 = (const float*)d_in[18]; const float* att2 = (const float*)d_in[19];
  const float* bias2 = (const float*)d_in[20];
  const float* Wih = (const float*)d_in[21]; const float* bih = (const float*)d_in[22];
  const float* Whh = (const float*)d_in[23]; const float* bhh = (const float*)d_in[24];
  const float* rW1 = (const float*)d_in[25]; const float* rb1 = (const float*)d_in[26];
  const float* rW2 = (const float*)d_in[27]; const float* rb2 = (const float*)d_in[28];
  const float* wW1 = (const float*)d_in[29]; const float* wb1 = (const float*)d_in[30];
  const float* wW2 = (const float*)d_in[31]; const float* wb2 = (const float*)d_in[32];
  const float* pW1 = (const float*)d_in[33]; const float* pb1 = (const float*)d_in[34];
  const float* pW2 = (const float*)d_in[35]; const float* pb2 = (const float*)d_in[36];
  const float* dW1 = (const float*)d_in[37]; const float* db1 = (const float*)d_in[38];
  const float* dW2 = (const float*)d_in[39]; const float* db2 = (const float*)d_in[40];

  const int* src = edges;
  const int* dst = edges + E_RAW;

  float* base = (float*)d_ws;
  size_t cur = 0;
  auto alloc = [&](size_t n) { float* p = base + cur; cur += (n + 63) & ~(size_t)63; return p; };

  float* BIG0 = alloc(8388608);   // XLR2 (bf16, xr half live) -> T (bf16)
  float* BIG1 = alloc(6291456);   // x_bf (bf16)
  float* XLR1f = alloc(2097152);  // [8192][512] bf16 (xr half live)
  float* XL8f = alloc(2097152);   // [8192][1024] fp8 conv2
  float* XL81f = alloc(524288);   // [8192][256] fp8 conv1
  float* X1f  = alloc(1048576);
  float* X2f  = alloc(1048576);
  float* Hbf  = alloc(1048576);
  float* HNbf = alloc(1048576);
  float* WT1f = alloc(212992);
  float* WT2f = alloc(262144);
  float* WTihf = alloc(98304);
  float* WThhf = alloc(98304);
  float* WThf  = alloc(98304);
  float* B1 = alloc(512);
  float* B2 = alloc(2048);
  float* BH = alloc(768);
  float* EAV = alloc(E_TOT);
  float* AP  = alloc(N_NODES);
  float* MP  = alloc(320);
  int* ICNT = (int*)alloc(2 * N_NODES + 64);  // ICNT | IPOS | DPOS contiguous
  int* IOFF = (int*)alloc(N_NODES + 64);
  int* ISRC = (int*)alloc(E_TOT);
  int* DOFF = (int*)alloc(64);
  int* PERM = (int*)alloc(N_NODES);
  if (ws_size < cur * 4) return;
  int* IPOS = ICNT + N_NODES;
  int* DPOS = IPOS + N_NODES;

  __hip_bfloat16* x_bf = (__hip_bfloat16*)BIG1;
  __hip_bfloat16* XLR1 = (__hip_bfloat16*)XLR1f;
  __hip_bfloat16* XLR2 = (__hip_bfloat16*)BIG0;
  unsigned char* XL8 = (unsigned char*)XL8f;
  unsigned char* XL81 = (unsigned char*)XL81f;
  __hip_bfloat16* X1b = (__hip_bfloat16*)X1f;
  __hip_bfloat16* X2b = (__hip_bfloat16*)X2f;
  __hip_bfloat16* Hb  = (__hip_bfloat16*)Hbf;
  __hip_bfloat16* HNb = (__hip_bfloat16*)HNbf;
  __hip_bfloat16* WT1 = (__hip_bfloat16*)WT1f;
  __hip_bfloat16* WT2 = (__hip_bfloat16*)WT2f;
  __hip_bfloat16* WTih = (__hip_bfloat16*)WTihf;
  __hip_bfloat16* WThh = (__hip_bfloat16*)WThhf;
  __hip_bfloat16* WTh  = (__hip_bfloat16*)WThf;
  __hip_bfloat16* Tb = (__hip_bfloat16*)BIG0;

  float* o_hnew = (float*)d_out;
  float* o_res  = o_hnew + (size_t)N_NODES * 256;
  float* o_w    = o_res + (size_t)N_NODES * 2;
  float* o_ap   = o_w + (size_t)N_NODES * 2;
  float* o_ad   = o_ap + 4;

  // ---- prep ----
  prep_kernel<<<9550, 256, 0, stream>>>(c_temp, c_stereo, e_proj, f_Lt, h, eattr,
                                        bl1, br1, bl2, br2, rb1, wb1, pb1, db1,
                                        x_bf, Hb, MP, ICNT, B1, B2, BH);
  csr_count<<<(E_TOT + 255) / 256, 256, 0, stream>>>(dst, ICNT);
  csr_scan<<<1, 1024, 0, stream>>>(ICNT, IOFF, MP, DOFF);
  csr_fill<<<576, 256, 0, stream>>>(src, dst, eattr, MP + 256, IOFF, IPOS, ISRC, EAV,
                                    ICNT, DOFF, DPOS, PERM);
  wt_all<<<1504, 256, 0, stream>>>(Wl1, Wr1, Wl2, Wr2, Wih, Whh, rW1, wW1, pW1, dW1,
                                   WT1, WT2, WTih, WThh, WTh);

  // ---- conv1 (fp8 xl + bf16 xr) ----
  mfma_gemm<6><<<dim3(4, 64), 512, 0, stream>>>(x_bf, WT1, B1, XLR1, 832, 512, XL81);
  gat_fused1<<<N_NODES / 4, 256, 0, stream>>>(XL81, XLR1, IOFF, ISRC, EAV, PERM,
                                              We1, att1, bias1, X1b);

  // ---- conv2 (fp8 xl + bf16 xr) ----
  mfma_gemm<7><<<dim3(16, 64), 512, 0, stream>>>(X1b, WT2, B2, XLR2, 256, 2048, XL8);
  gat_fused2<<<N_NODES / 4, 256, 0, stream>>>(XL8, XLR2, IOFF, ISRC, EAV, PERM,
                                              We2, att2, bias2, X2b);

  // ---- GRU (fused GEMM + elementwise; 512 blocks for 2/CU overlap) ----
  gru_gemm<<<dim3(2, 256), 256, 0, stream>>>(X2b, Hb, WTih, WThh, bih, bhh, h, o_hnew, HNb);

  // ---- heads ----
  mfma_gemm<3><<<dim3(6, 64), 512, 0, stream>>>(HNb, WTh, BH, Tb, 256, 768, nullptr);
  heads_final<<<N_NODES / 4, 256, 0, stream>>>(Tb, rW2, rb2, wW2, wb2, pW2, pb2, dW2, db2,
                                               o_res, o_w, AP, o_ad);
  ap_reduce<<<4, 256, 0, stream>>>(AP, o_ap);
}

// Round 16
// 201.488 us; speedup vs baseline: 1.0343x; 1.0343x over previous
//
#include <hip/hip_runtime.h>
#include <hip/hip_bf16.h>
#include <cstdint>
#include <cstddef>

#define N_NODES 8192
#define E_RAW   131072
#define E_TOT   (E_RAW + N_NODES)   // 139264
#define HEADS   4

typedef __attribute__((ext_vector_type(8))) __bf16 bf16x8;
typedef __attribute__((ext_vector_type(4))) float f32x4;
typedef __attribute__((ext_vector_type(2))) float f32x2;

__device__ __forceinline__ void gload_lds16(const void* g, void* lds) {
  __builtin_amdgcn_global_load_lds(
      (const __attribute__((address_space(1))) unsigned int*)g,
      (__attribute__((address_space(3))) unsigned int*)lds, 16, 0, 0);
}

__device__ __forceinline__ float bfbits2f(unsigned short u) {
  return __uint_as_float((unsigned)u << 16);
}
__device__ __forceinline__ unsigned short f2bfbits(float f) {
  __hip_bfloat16 b = __float2bfloat16(f);
  return *(unsigned short*)&b;
}
__device__ __forceinline__ f32x2 unpk2(unsigned u) {
  return (f32x2){__uint_as_float(u << 16), __uint_as_float(u & 0xffff0000u)};
}
__device__ __forceinline__ unsigned char f32_to_fp8(float v) {
  int r = __builtin_amdgcn_cvt_pk_fp8_f32(v, v, 0, false);
  return (unsigned char)(r & 0xff);
}

__device__ __forceinline__ int eSrc(const int* __restrict__ src, int e) {
  return (e < E_RAW) ? src[e] : (e - E_RAW);
}
__device__ __forceinline__ int eDst(const int* __restrict__ dst, int e) {
  return (e < E_RAW) ? dst[e] : (e - E_RAW);
}

// ---------------- fused prep ----------------

__global__ __launch_bounds__(256) void prep_kernel(
    const float* __restrict__ ct, const float* __restrict__ cs,
    const float* __restrict__ ep, const float* __restrict__ fl,
    const float* __restrict__ h, const float* __restrict__ ea,
    const float* bl1, const float* br1, const float* bl2, const float* br2,
    const float* rb1, const float* wb1, const float* pb1, const float* db1,
    __hip_bfloat16* __restrict__ x, __hip_bfloat16* __restrict__ Hb,
    float* __restrict__ MP, int* __restrict__ icnt_ipos,
    float* B1, float* B2, float* BH) {
  int blk = blockIdx.x;
  int tid = threadIdx.x;
  if (blk < 8192) {
    int i = blk;
    for (int j = tid; j < 832; j += 256) {
      float v;
      if (j < 256)      v = ct[(size_t)i * 256 + j];
      else if (j < 512) v = cs[(size_t)i * 256 + (j - 256)];
      else if (j < 514) v = ep[(size_t)i * 2 + (j - 512)];
      else if (j < 770) v = fl[(size_t)i * 256 + (j - 514)];
      else              v = 0.f;
      x[(size_t)i * 832 + j] = __float2bfloat16(v);
    }
  } else if (blk < 9216) {
    size_t base = ((size_t)(blk - 8192) * 256 + tid) * 8;
    float4 a = *(const float4*)(h + base);
    float4 b = *(const float4*)(h + base + 4);
    unsigned short o[8];
    o[0]=f2bfbits(a.x); o[1]=f2bfbits(a.y); o[2]=f2bfbits(a.z); o[3]=f2bfbits(a.w);
    o[4]=f2bfbits(b.x); o[5]=f2bfbits(b.y); o[6]=f2bfbits(b.z); o[7]=f2bfbits(b.w);
    *(uint4*)((unsigned short*)Hb + base) = *(uint4*)o;
  } else if (blk < 9472) {
    __shared__ float sm[256];
    int bb = blk - 9216;
    float acc = 0.f;
    for (int i = bb * 256 + tid; i < E_RAW; i += 256 * 256) acc += ea[i];
    sm[tid] = acc; __syncthreads();
    for (int s = 128; s; s >>= 1) { if (tid < s) sm[tid] += sm[tid + s]; __syncthreads(); }
    if (tid == 0) MP[bb] = sm[0];
  } else if (blk < 9536) {
    int i = (blk - 9472) * 256 + tid;
    if (i < 2 * N_NODES) icnt_ipos[i] = 0;
  } else {
    int i = (blk - 9536) * 256 + tid;
    if (i < 512) B1[i] = (i < 256) ? bl1[i] : br1[i - 256];
    else if (i < 2560) { int k = i - 512; B2[k] = (k < 1024) ? bl2[k] : br2[k - 1024]; }
    else if (i < 3328) {
      int k = i - 2560;
      BH[k] = (k < 256) ? rb1[k] : (k < 512) ? wb1[k - 256] : (k < 640) ? pb1[k - 512] : db1[k - 640];
    }
  }
}

// ---------------- CSR build ----------------

__global__ void csr_count(const int* __restrict__ dst, int* __restrict__ cnt) {
  int e = blockIdx.x * blockDim.x + threadIdx.x;
  if (e < E_TOT) atomicAdd(&cnt[eDst(dst, e)], 1);
}

__global__ __launch_bounds__(1024) void csr_scan(const int* __restrict__ cnt,
                                                 int* __restrict__ off,
                                                 float* __restrict__ MP) {
  __shared__ int part[1024];
  __shared__ float sm[256];
  int t = threadIdx.x;
  if (t < 256) sm[t] = MP[t];
  __syncthreads();
  for (int s = 128; s; s >>= 1) { if (t < s) sm[t] += sm[t + s]; __syncthreads(); }
  if (t == 0) MP[256] = sm[0] * (1.f / (float)E_RAW);
  int base = t * 8;
  int loc[8];
  int s = 0;
#pragma unroll
  for (int i = 0; i < 8; ++i) { loc[i] = s; s += cnt[base + i]; }
  part[t] = s; __syncthreads();
  for (int d = 1; d < 1024; d <<= 1) {
    int v = (t >= d) ? part[t - d] : 0;
    __syncthreads();
    part[t] += v;
    __syncthreads();
  }
  int pre = (t == 0) ? 0 : part[t - 1];
#pragma unroll
  for (int i = 0; i < 8; ++i) off[base + i] = pre + loc[i];
  if (t == 1023) off[8192] = part[1023];
}

__global__ void csr_fill(const int* __restrict__ src, const int* __restrict__ dst,
                         const float* __restrict__ ea, const float* __restrict__ eamean,
                         const int* __restrict__ off, int* __restrict__ pos,
                         int* __restrict__ srcn, float* __restrict__ eav) {
  int e = blockIdx.x * blockDim.x + threadIdx.x;
  if (e >= E_TOT) return;
  int d = eDst(dst, e);
  int p = off[d] + atomicAdd(&pos[d], 1);
  srcn[p] = eSrc(src, e);
  eav[p] = (e < E_RAW) ? ea[e] : eamean[0];
}

// ---------------- all weight transposes ----------------

__global__ __launch_bounds__(256) void wt_all(
    const float* w0, const float* w1, const float* w2, const float* w3,
    const float* w4, const float* w5, const float* w6, const float* w7,
    const float* w8, const float* w9,
    __hip_bfloat16* WT1, __hip_bfloat16* WT2, __hip_bfloat16* WTih,
    __hip_bfloat16* WThh, __hip_bfloat16* WTh) {
  const int cum[10] = {208, 416, 672, 928, 1120, 1312, 1376, 1440, 1472, 1504};
  const int Kt[10]  = {770, 770, 256, 256, 256, 256, 256, 256, 256, 256};
  const int Nt[10]  = {256, 256, 1024, 1024, 768, 768, 256, 256, 128, 128};
  const int KPt[10] = {832, 832, 256, 256, 256, 256, 256, 256, 256, 256};
  const int n0t[10] = {0, 256, 0, 1024, 0, 0, 0, 256, 512, 640};
  int job = 0;
  while (blockIdx.x >= (unsigned)cum[job]) ++job;
  int lb = blockIdx.x - (job ? cum[job - 1] : 0);
  int K = Kt[job], N = Nt[job], KP = KPt[job], n0 = n0t[job];
  int tilesX = KP >> 5;
  int k0 = (lb % tilesX) * 32, nb = (lb / tilesX) * 32;
  const float* W;
  switch (job) {
    case 0: W = w0; break; case 1: W = w1; break; case 2: W = w2; break;
    case 3: W = w3; break; case 4: W = w4; break; case 5: W = w5; break;
    case 6: W = w6; break; case 7: W = w7; break; case 8: W = w8; break;
    default: W = w9; break;
  }
  __hip_bfloat16* WT = (job < 2) ? WT1 : (job < 4) ? WT2 : (job == 4) ? WTih
                       : (job == 5) ? WThh : WTh;
  __shared__ float sm[32][33];
  int tx = threadIdx.x & 31, ty = threadIdx.x >> 5;
  for (int yy = ty; yy < 32; yy += 8) {
    int k = k0 + yy, n = nb + tx;
    sm[yy][tx] = (k < K && n < N) ? W[(size_t)k * N + n] : 0.f;
  }
  __syncthreads();
  for (int yy = ty; yy < 32; yy += 8) {
    int n = nb + yy, k = k0 + tx;
    if (n < N) WT[(size_t)(n0 + n) * KP + k] = __float2bfloat16(sm[tx][yy]);
  }
}

// ---------------- bf16 MFMA GEMM (128x128 tile, 8 waves of 32x64, BK=64, swizzled LDS) ----------------
// OUT: 0 bf16 all | 3 bf16 relu all
//      6 conv1: fp8 (cols<256, stride 256) + bf16 only cols>=256
//      7 conv2: fp8 (cols<1024, stride 1024) + bf16 only cols>=1024

template <int OUT>
__global__ __launch_bounds__(512) void mfma_gemm(
    const __hip_bfloat16* __restrict__ A, const __hip_bfloat16* __restrict__ BT,
    const float* __restrict__ bias, void* __restrict__ Cout, int KP, int N,
    unsigned char* __restrict__ Cfp8) {
  __shared__ uint4 AsBuf[1024];
  __shared__ uint4 BsBuf[1024];
  char* Asc = (char*)AsBuf;
  char* Bsc = (char*)BsBuf;
  int tid = threadIdx.x;
  int lane = tid & 63;
  int wid = tid >> 6;
  int wr = wid >> 1;
  int wc = wid & 1;
  int bm = blockIdx.y * 128;
  int bn = blockIdx.x * 128;
  f32x4 acc[2][4];
#pragma unroll
  for (int i = 0; i < 2; ++i)
#pragma unroll
    for (int j = 0; j < 4; ++j) acc[i][j] = (f32x4){0.f, 0.f, 0.f, 0.f};

  int nK = KP >> 6;
  for (int kt = 0; kt < nK; ++kt) {
    int k0 = kt * 64;
#pragma unroll
    for (int i = 0; i < 2; ++i) {
      int p = i * 512 + tid;
      int row = p >> 3, cc = p & 7;
      int sc = cc ^ (row & 7);
      gload_lds16(A + (size_t)(bm + row) * KP + k0 + sc * 8, Asc + p * 16);
      gload_lds16(BT + (size_t)(bn + row) * KP + k0 + sc * 8, Bsc + p * 16);
    }
    __syncthreads();
#pragma unroll
    for (int s = 0; s < 2; ++s) {
      bf16x8 af[2], bfr[4];
#pragma unroll
      for (int f = 0; f < 2; ++f) {
        int r = wr * 32 + f * 16 + (lane & 15);
        int ch = (s * 4 + (lane >> 4)) ^ (r & 7);
        af[f] = *(const bf16x8*)(Asc + r * 128 + ch * 16);
      }
#pragma unroll
      for (int f = 0; f < 4; ++f) {
        int n = wc * 64 + f * 16 + (lane & 15);
        int cb = (s * 4 + (lane >> 4)) ^ (n & 7);
        bfr[f] = *(const bf16x8*)(Bsc + n * 128 + cb * 16);
      }
#pragma unroll
      for (int fm = 0; fm < 2; ++fm)
#pragma unroll
        for (int fn = 0; fn < 4; ++fn)
          acc[fm][fn] = __builtin_amdgcn_mfma_f32_16x16x32_bf16(af[fm], bfr[fn], acc[fm][fn], 0, 0, 0);
    }
    __syncthreads();
  }
  int rbase = bm + wr * 32 + (lane >> 4) * 4;
  int cbase = bn + wc * 64 + (lane & 15);
#pragma unroll
  for (int fm = 0; fm < 2; ++fm)
#pragma unroll
    for (int fn = 0; fn < 4; ++fn) {
      int col = cbase + fn * 16;
      float bv = bias[col];
#pragma unroll
      for (int j = 0; j < 4; ++j) {
        int row = rbase + fm * 16 + j;
        float v = acc[fm][fn][j] + bv;
        if (OUT == 3) v = fmaxf(v, 0.f);
        if (OUT == 0 || OUT == 3)
          ((__hip_bfloat16*)Cout)[(size_t)row * N + col] = __float2bfloat16(v);
        if (OUT == 6) {
          if (col < 256) Cfp8[(size_t)row * 256 + col] = f32_to_fp8(v);
          else ((__hip_bfloat16*)Cout)[(size_t)row * N + col] = __float2bfloat16(v);
        }
        if (OUT == 7) {
          if (col < 1024) Cfp8[(size_t)row * 1024 + col] = f32_to_fp8(v);
          else ((__hip_bfloat16*)Cout)[(size_t)row * N + col] = __float2bfloat16(v);
        }
      }
    }
}

// ---------------- fused GATv2 conv1: 1 wave/node, fp8 gathers (1-deep prefetch) ----------------

__global__ __launch_bounds__(256) void gat_fused1(
    const unsigned char* __restrict__ XL8,   // [n][256] fp8 xl
    const __hip_bfloat16* __restrict__ XLR,  // [n][512] (xr half at +256)
    const int* __restrict__ off, const int* __restrict__ srcn,
    const float* __restrict__ eav, const float* __restrict__ We,
    const float* __restrict__ att, const float* __restrict__ bias,
    __hip_bfloat16* __restrict__ X1) {
  int d = (blockIdx.x * 256 + threadIdx.x) >> 6;
  int lane = threadIdx.x & 63;
  int q = lane & 15;
  int j0 = (lane >> 4) * 64 + q * 4;
  const unsigned short* X = (const unsigned short*)XLR;
  uint2 xv = *(const uint2*)(X + (size_t)d * 512 + 256 + j0);
  f32x2 xr[2] = {unpk2(xv.x), unpk2(xv.y)};
  f32x2 we[2] = {*(const f32x2*)(We + j0), *(const f32x2*)(We + j0 + 2)};
  f32x2 at[2] = {*(const f32x2*)(att + j0), *(const f32x2*)(att + j0 + 2)};
  int b = off[d], e1 = off[d + 1], pe = e1 - 1;
  int sB = srcn[b]; float eaA = eav[b];
  unsigned rA = *(const unsigned*)(XL8 + (size_t)sB * 256 + j0);
  int p1 = min(b + 1, pe); sB = srcn[p1]; float eaB = eav[p1];
  float m = -INFINITY, ss = 0.f;
  f32x2 a[2] = {(f32x2){0.f, 0.f}, (f32x2){0.f, 0.f}};
  for (int p = b; p < e1; ++p) {
    unsigned cc = rA; float ea = eaA; eaA = eaB;
    rA = *(const unsigned*)(XL8 + (size_t)sB * 256 + j0);
    int p2 = min(p + 2, pe); sB = srcn[p2]; eaB = eav[p2];
    f32x2 v[2];
    v[0] = (f32x2){__builtin_amdgcn_cvt_f32_fp8(cc, 0), __builtin_amdgcn_cvt_f32_fp8(cc, 1)};
    v[1] = (f32x2){__builtin_amdgcn_cvt_f32_fp8(cc, 2), __builtin_amdgcn_cvt_f32_fp8(cc, 3)};
    f32x2 ea2 = (f32x2){ea, ea};
    f32x2 t2 = (f32x2){0.f, 0.f};
#pragma unroll
    for (int i = 0; i < 2; ++i) {
      f32x2 gg = (v[i] + xr[i]) + ea2 * we[i];
      f32x2 lr = __builtin_elementwise_max(gg, 0.2f * gg);
      t2 = t2 + lr * at[i];
    }
    float t = t2.x + t2.y;
    t += __shfl_xor(t, 8, 64); t += __shfl_xor(t, 4, 64);
    t += __shfl_xor(t, 2, 64); t += __shfl_xor(t, 1, 64);
    if (__all(t <= m)) {
      float wp = __expf(t - m);
      ss += wp;
      f32x2 wp2 = (f32x2){wp, wp};
#pragma unroll
      for (int i = 0; i < 2; ++i) a[i] = a[i] + wp2 * v[i];
    } else {
      float mn = fmaxf(m, t);
      float scl = __expf(m - mn);
      float wp = __expf(t - mn);
      ss = fmaf(ss, scl, wp);
      f32x2 wp2 = (f32x2){wp, wp}, s2 = (f32x2){scl, scl};
#pragma unroll
      for (int i = 0; i < 2; ++i) a[i] = a[i] * s2 + wp2 * v[i];
      m = mn;
    }
  }
  float inv = 1.f / (ss + 1e-16f);
  unsigned short o[4];
  o[0] = f2bfbits(fmaxf(fmaf(a[0].x, inv, bias[j0]), 0.f));
  o[1] = f2bfbits(fmaxf(fmaf(a[0].y, inv, bias[j0 + 1]), 0.f));
  o[2] = f2bfbits(fmaxf(fmaf(a[1].x, inv, bias[j0 + 2]), 0.f));
  o[3] = f2bfbits(fmaxf(fmaf(a[1].y, inv, bias[j0 + 3]), 0.f));
  *(uint2*)((unsigned short*)X1 + (size_t)d * 256 + j0) = *(uint2*)o;
}

// ---------------- fused GATv2 conv2: 1 wave/node, fp8 gathers (1-deep), head-mean ----------------

__global__ __launch_bounds__(256) void gat_fused2(
    const unsigned char* __restrict__ XL8,   // [n][1024] fp8 e4m3
    const __hip_bfloat16* __restrict__ XLR,  // [n][2048] (xr half at +1024)
    const int* __restrict__ off, const int* __restrict__ srcn,
    const float* __restrict__ eav, const float* __restrict__ We,
    const float* __restrict__ att, const float* __restrict__ bias,
    __hip_bfloat16* __restrict__ X2) {
  int d = (blockIdx.x * 256 + threadIdx.x) >> 6;
  int lane = threadIdx.x & 63;
  int g = lane >> 4, q = lane & 15;
  int j0 = g * 256 + q * 16;
  const unsigned short* X = (const unsigned short*)XLR;
  f32x2 xr[8], we[8], at[8], a[8];
  {
    const uint4* xp = (const uint4*)(X + (size_t)d * 2048 + 1024 + j0);
    uint4 r0 = xp[0], r1 = xp[1];
    xr[0] = unpk2(r0.x); xr[1] = unpk2(r0.y); xr[2] = unpk2(r0.z); xr[3] = unpk2(r0.w);
    xr[4] = unpk2(r1.x); xr[5] = unpk2(r1.y); xr[6] = unpk2(r1.z); xr[7] = unpk2(r1.w);
#pragma unroll
    for (int i = 0; i < 8; ++i) {
      we[i] = *(const f32x2*)(We + j0 + 2 * i);
      at[i] = *(const f32x2*)(att + j0 + 2 * i);
      a[i] = (f32x2){0.f, 0.f};
    }
  }
  int b = off[d], e1 = off[d + 1], pe = e1 - 1;
  int sB = srcn[b]; float eaA = eav[b];
  uint4 rA = *(const uint4*)(XL8 + (size_t)sB * 1024 + j0);
  int p1 = min(b + 1, pe); sB = srcn[p1]; float eaB = eav[p1];
  float m = -INFINITY, ss = 0.f;
  for (int p = b; p < e1; ++p) {
    uint4 cc = rA; float ea = eaA; eaA = eaB;
    rA = *(const uint4*)(XL8 + (size_t)sB * 1024 + j0);
    int p2 = min(p + 2, pe); sB = srcn[p2]; eaB = eav[p2];
    f32x2 v[8];
    v[0] = (f32x2){__builtin_amdgcn_cvt_f32_fp8(cc.x, 0), __builtin_amdgcn_cvt_f32_fp8(cc.x, 1)};
    v[1] = (f32x2){__builtin_amdgcn_cvt_f32_fp8(cc.x, 2), __builtin_amdgcn_cvt_f32_fp8(cc.x, 3)};
    v[2] = (f32x2){__builtin_amdgcn_cvt_f32_fp8(cc.y, 0), __builtin_amdgcn_cvt_f32_fp8(cc.y, 1)};
    v[3] = (f32x2){__builtin_amdgcn_cvt_f32_fp8(cc.y, 2), __builtin_amdgcn_cvt_f32_fp8(cc.y, 3)};
    v[4] = (f32x2){__builtin_amdgcn_cvt_f32_fp8(cc.z, 0), __builtin_amdgcn_cvt_f32_fp8(cc.z, 1)};
    v[5] = (f32x2){__builtin_amdgcn_cvt_f32_fp8(cc.z, 2), __builtin_amdgcn_cvt_f32_fp8(cc.z, 3)};
    v[6] = (f32x2){__builtin_amdgcn_cvt_f32_fp8(cc.w, 0), __builtin_amdgcn_cvt_f32_fp8(cc.w, 1)};
    v[7] = (f32x2){__builtin_amdgcn_cvt_f32_fp8(cc.w, 2), __builtin_amdgcn_cvt_f32_fp8(cc.w, 3)};
    f32x2 ea2 = (f32x2){ea, ea};
    f32x2 t2 = (f32x2){0.f, 0.f};
#pragma unroll
    for (int i = 0; i < 8; ++i) {
      f32x2 gg = (v[i] + xr[i]) + ea2 * we[i];
      f32x2 lr = __builtin_elementwise_max(gg, 0.2f * gg);
      t2 = t2 + lr * at[i];
    }
    float t = t2.x + t2.y;
    t += __shfl_xor(t, 8, 64); t += __shfl_xor(t, 4, 64);
    t += __shfl_xor(t, 2, 64); t += __shfl_xor(t, 1, 64);
    if (__all(t <= m)) {
      float wp = __expf(t - m);
      ss += wp;
      f32x2 wp2 = (f32x2){wp, wp};
#pragma unroll
      for (int i = 0; i < 8; ++i) a[i] = a[i] + wp2 * v[i];
    } else {
      float mn = fmaxf(m, t);
      float scl = __expf(m - mn);
      float wp = __expf(t - mn);
      ss = fmaf(ss, scl, wp);
      f32x2 wp2 = (f32x2){wp, wp}, s2 = (f32x2){scl, scl};
#pragma unroll
      for (int i = 0; i < 8; ++i) a[i] = a[i] * s2 + wp2 * v[i];
      m = mn;
    }
  }
  float inv = 1.f / (ss + 1e-16f);
  f32x2 inv2 = (f32x2){inv, inv};
#pragma unroll
  for (int i = 0; i < 8; ++i) {
    f32x2 r2 = a[i] * inv2;
    r2.x += __shfl_xor(r2.x, 16, 64);
    r2.x += __shfl_xor(r2.x, 32, 64);
    r2.y += __shfl_xor(r2.y, 16, 64);
    r2.y += __shfl_xor(r2.y, 32, 64);
    a[i] = r2;
  }
  if (g == 0) {
    unsigned short o[16];
#pragma unroll
    for (int i = 0; i < 8; ++i) {
      o[2 * i]     = f2bfbits(fmaf(0.25f, a[i].x, bias[q * 16 + 2 * i]));
      o[2 * i + 1] = f2bfbits(fmaf(0.25f, a[i].y, bias[q * 16 + 2 * i + 1]));
    }
    uint4* op = (uint4*)((unsigned short*)X2 + (size_t)d * 256 + q * 16);
    op[0] = ((uint4*)o)[0];
    op[1] = ((uint4*)o)[1];
  }
}

// ---------------- fused GRU GEMM: all 3 gates for gi & gh + elementwise, 64x128 tile ----------------
// grid (2, 128): bx -> gate-local cols [bx*128, bx*128+128), by -> rows [by*64, +64)
// waves: wr=wid>>1 (4x16 rows), wc=wid&1 (2x64 cols). K=256. Gates sequential.

__global__ __launch_bounds__(512) void gru_gemm(
    const __hip_bfloat16* __restrict__ X2b,  // [8192][256]
    const __hip_bfloat16* __restrict__ Hb,   // [8192][256]
    const __hip_bfloat16* __restrict__ WTih, // [768][256]
    const __hip_bfloat16* __restrict__ WThh, // [768][256]
    const float* __restrict__ bih, const float* __restrict__ bhh,
    const float* __restrict__ hf,
    float* __restrict__ hn, __hip_bfloat16* __restrict__ hnb) {
  __shared__ uint4 AxB[512];   // 8KB: 64 rows x 64 k
  __shared__ uint4 AhB[512];
  __shared__ uint4 BiB[1024];  // 16KB: 128 n x 64 k
  __shared__ uint4 BhB[1024];
  char* Ax = (char*)AxB;
  char* Ah = (char*)AhB;
  char* Bi = (char*)BiB;
  char* Bh = (char*)BhB;
  int tid = threadIdx.x;
  int lane = tid & 63, wid = tid >> 6;
  int wr = wid >> 1, wc = wid & 1;
  int bm = blockIdx.y * 64;
  int c0 = blockIdx.x * 128;
  float rv[16], zv[16];
  float outv[16];
  for (int gate = 0; gate < 3; ++gate) {
    f32x4 ai[4], ah[4];
#pragma unroll
    for (int j = 0; j < 4; ++j) { ai[j] = (f32x4){0.f,0.f,0.f,0.f}; ah[j] = (f32x4){0.f,0.f,0.f,0.f}; }
    for (int kt = 0; kt < 4; ++kt) {
      int k0 = kt * 64;
      {
        int p = tid;
        int row = p >> 3, cc = p & 7;
        int sc = cc ^ (row & 7);
        gload_lds16(X2b + (size_t)(bm + row) * 256 + k0 + sc * 8, Ax + p * 16);
        gload_lds16(Hb + (size_t)(bm + row) * 256 + k0 + sc * 8, Ah + p * 16);
      }
#pragma unroll
      for (int i = 0; i < 2; ++i) {
        int p = i * 512 + tid;
        int row = p >> 3, cc = p & 7;
        int sc = cc ^ (row & 7);
        int n = gate * 256 + c0 + row;
        gload_lds16(WTih + (size_t)n * 256 + k0 + sc * 8, Bi + p * 16);
        gload_lds16(WThh + (size_t)n * 256 + k0 + sc * 8, Bh + p * 16);
      }
      __syncthreads();
#pragma unroll
      for (int s = 0; s < 2; ++s) {
        int rl = wr * 16 + (lane & 15);
        int ch = (s * 4 + (lane >> 4)) ^ (rl & 7);
        bf16x8 axf = *(const bf16x8*)(Ax + rl * 128 + ch * 16);
        bf16x8 ahf = *(const bf16x8*)(Ah + rl * 128 + ch * 16);
        bf16x8 bif[4], bhf[4];
#pragma unroll
        for (int f = 0; f < 4; ++f) {
          int nl = wc * 64 + f * 16 + (lane & 15);
          int cb = (s * 4 + (lane >> 4)) ^ (nl & 7);
          bif[f] = *(const bf16x8*)(Bi + nl * 128 + cb * 16);
          bhf[f] = *(const bf16x8*)(Bh + nl * 128 + cb * 16);
        }
#pragma unroll
        for (int fn = 0; fn < 4; ++fn) {
          ai[fn] = __builtin_amdgcn_mfma_f32_16x16x32_bf16(axf, bif[fn], ai[fn], 0, 0, 0);
          ah[fn] = __builtin_amdgcn_mfma_f32_16x16x32_bf16(ahf, bhf[fn], ah[fn], 0, 0, 0);
        }
      }
      __syncthreads();
    }
    // gate epilogue (per-lane 16 values)
#pragma unroll
    for (int fn = 0; fn < 4; ++fn) {
      int colL = wc * 64 + fn * 16 + (lane & 15);
      int ng = gate * 256 + c0 + colL;
      float bi_v = bih[ng], bh_v = bhh[ng];
#pragma unroll
      for (int j = 0; j < 4; ++j) {
        int k = fn * 4 + j;
        float vi = ai[fn][j] + bi_v;
        float vh = ah[fn][j] + bh_v;
        if (gate == 0) rv[k] = 1.f / (1.f + __expf(-(vi + vh)));
        else if (gate == 1) zv[k] = 1.f / (1.f + __expf(-(vi + vh)));
        else outv[k] = tanhf(vi + rv[k] * vh);
      }
    }
  }
  // final GRU blend + store
#pragma unroll
  for (int fn = 0; fn < 4; ++fn) {
    int colL = wc * 64 + fn * 16 + (lane & 15);
    int chn = c0 + colL;           // channel in [0,256)
#pragma unroll
    for (int j = 0; j < 4; ++j) {
      int k = fn * 4 + j;
      int row = bm + wr * 16 + (lane >> 4) * 4 + j;
      float h0 = hf[(size_t)row * 256 + chn];
      float v = (1.f - zv[k]) * outv[k] + zv[k] * h0;
      hn[(size_t)row * 256 + chn] = v;
      hnb[(size_t)row * 256 + chn] = __float2bfloat16(v);
    }
  }
}

// ---------------- all 4 final heads (bf16 T input) ----------------

__global__ __launch_bounds__(256) void heads_final(
    const __hip_bfloat16* __restrict__ Tb,
    const float* __restrict__ rW2, const float* __restrict__ rb2,
    const float* __restrict__ wW2, const float* __restrict__ wb2,
    const float* __restrict__ pW2, const float* __restrict__ pb2,
    const float* __restrict__ dW2, const float* __restrict__ db2,
    float* __restrict__ o_res, float* __restrict__ o_w,
    float* __restrict__ AP, float* __restrict__ o_ad) {
  int node = (blockIdx.x * 256 + threadIdx.x) >> 6;
  int lane = threadIdx.x & 63;
  const unsigned short* t = (const unsigned short*)Tb + (size_t)node * 768;
  ushort4 tr = *(const ushort4*)(t + lane * 4);
  ushort4 tw = *(const ushort4*)(t + 256 + lane * 4);
  float trf[4] = {bfbits2f(tr.x), bfbits2f(tr.y), bfbits2f(tr.z), bfbits2f(tr.w)};
  float twf[4] = {bfbits2f(tw.x), bfbits2f(tw.y), bfbits2f(tw.z), bfbits2f(tw.w)};
  float tpf[4] = {0.f, 0.f, 0.f, 0.f}, tdf[4] = {0.f, 0.f, 0.f, 0.f};
  if (lane < 32) {
    ushort4 tp = *(const ushort4*)(t + 512 + lane * 4);
    ushort4 td = *(const ushort4*)(t + 640 + lane * 4);
    tpf[0] = bfbits2f(tp.x); tpf[1] = bfbits2f(tp.y); tpf[2] = bfbits2f(tp.z); tpf[3] = bfbits2f(tp.w);
    tdf[0] = bfbits2f(td.x); tdf[1] = bfbits2f(td.y); tdf[2] = bfbits2f(td.z); tdf[3] = bfbits2f(td.w);
  }
  float r0 = 0.f, r1 = 0.f, w0 = 0.f, w1 = 0.f, pp = 0.f, dd = 0.f;
#pragma unroll
  for (int i = 0; i < 4; ++i) {
    int k = lane * 4 + i;
    r0 = fmaf(trf[i], rW2[k * 2], r0);
    r1 = fmaf(trf[i], rW2[k * 2 + 1], r1);
    w0 = fmaf(twf[i], wW2[k * 2], w0);
    w1 = fmaf(twf[i], wW2[k * 2 + 1], w1);
  }
  if (lane < 32) {
#pragma unroll
    for (int i = 0; i < 4; ++i) {
      int k = lane * 4 + i;
      pp = fmaf(tpf[i], pW2[k], pp);
      dd = fmaf(tdf[i], dW2[k], dd);
    }
  }
#pragma unroll
  for (int o = 32; o; o >>= 1) {
    r0 += __shfl_xor(r0, o, 64); r1 += __shfl_xor(r1, o, 64);
    w0 += __shfl_xor(w0, o, 64); w1 += __shfl_xor(w1, o, 64);
    pp += __shfl_xor(pp, o, 64); dd += __shfl_xor(dd, o, 64);
  }
  if (lane == 0) {
    o_res[(size_t)node * 2]     = r0 + rb2[0];
    o_res[(size_t)node * 2 + 1] = r1 + rb2[1];
    float sw0 = w0 + wb2[0], sw1 = w1 + wb2[1];
    o_w[(size_t)node * 2]     = 1.f / (1.f + __expf(-sw0));
    o_w[(size_t)node * 2 + 1] = 1.f / (1.f + __expf(-sw1));
    float vp = pp + pb2[0];
    AP[node] = fmaxf(vp, 0.f) + log1pf(__expf(-fabsf(vp)));
    float vd = dd + db2[0];
    o_ad[node] = fmaxf(vd, 0.f) + log1pf(__expf(-fabsf(vd)));
  }
}

__global__ void ap_reduce(const float* __restrict__ ap, float* __restrict__ out) {
  __shared__ float sm[256];
  int b = blockIdx.x, tid = threadIdx.x;
  float acc = 0.f;
  for (int i = tid; i < 2048; i += 256) acc += ap[b * 2048 + i];
  sm[tid] = acc; __syncthreads();
  for (int s = 128; s; s >>= 1) { if (tid < s) sm[tid] += sm[tid + s]; __syncthreads(); }
  if (tid == 0) out[b] = sm[0] * (1.f / 2048.f);
}

// ---------------- launch ----------------

extern "C" void kernel_launch(void* const* d_in, const int* in_sizes, int n_in,
                              void* d_out, int out_size, void* d_ws, size_t ws_size,
                              hipStream_t stream) {
  const float* h        = (const float*)d_in[0];
  const float* c_temp   = (const float*)d_in[1];
  const float* c_stereo = (const float*)d_in[2];
  const float* e_proj   = (const float*)d_in[3];
  const float* f_Lt     = (const float*)d_in[4];
  const int*   edges    = (const int*)d_in[5];
  const float* eattr    = (const float*)d_in[6];
  const float* Wl1 = (const float*)d_in[7];  const float* bl1 = (const float*)d_in[8];
  const float* Wr1 = (const float*)d_in[9];  const float* br1 = (const float*)d_in[10];
  const float* We1 = (const float*)d_in[11]; const float* att1 = (const float*)d_in[12];
  const float* bias1 = (const float*)d_in[13];
  const float* Wl2 = (const float*)d_in[14]; const float* bl2 = (const float*)d_in[15];
  const float* Wr2 = (const float*)d_in[16]; const float* br2 = (const float*)d_in[17];
  const float* We2 = (const float*)d_in[18]; const float* att2 = (const float*)d_in[19];
  const float* bias2 = (const float*)d_in[20];
  const float* Wih = (const float*)d_in[21]; const float* bih = (const float*)d_in[22];
  const float* Whh = (const float*)d_in[23]; const float* bhh = (const float*)d_in[24];
  const float* rW1 = (const float*)d_in[25]; const float* rb1 = (const float*)d_in[26];
  const float* rW2 = (const float*)d_in[27]; const float* rb2 = (const float*)d_in[28];
  const float* wW1 = (const float*)d_in[29]; const float* wb1 = (const float*)d_in[30];
  const float* wW2 = (const float*)d_in[31]; const float* wb2 = (const float*)d_in[32];
  const float* pW1 = (const float*)d_in[33]; const float* pb1 = (const float*)d_in[34];
  const float* pW2 = (const float*)d_in[35]; const float* pb2 = (const float*)d_in[36];
  const float* dW1 = (const float*)d_in[37]; const float* db1 = (const float*)d_in[38];
  const float* dW2 = (const float*)d_in[39]; const float* db2 = (const float*)d_in[40];

  const int* src = edges;
  const int* dst = edges + E_RAW;

  float* base = (float*)d_ws;
  size_t cur = 0;
  auto alloc = [&](size_t n) { float* p = base + cur; cur += (n + 63) & ~(size_t)63; return p; };

  float* BIG0 = alloc(8388608);   // XLR2 (bf16, xr half live) -> T (bf16)
  float* BIG1 = alloc(6291456);   // x_bf (bf16)
  float* XLR1f = alloc(2097152);  // [8192][512] bf16 (xr half live)
  float* XL8f = alloc(2097152);   // [8192][1024] fp8 conv2
  float* XL81f = alloc(524288);   // [8192][256] fp8 conv1
  float* X1f  = alloc(1048576);
  float* X2f  = alloc(1048576);
  float* Hbf  = alloc(1048576);
  float* HNbf = alloc(1048576);
  float* WT1f = alloc(212992);
  float* WT2f = alloc(262144);
  float* WTihf = alloc(98304);
  float* WThhf = alloc(98304);
  float* WThf  = alloc(98304);
  float* B1 = alloc(512);
  float* B2 = alloc(2048);
  float* BH = alloc(768);
  float* EAV = alloc(E_TOT);
  float* AP  = alloc(N_NODES);
  float* MP  = alloc(320);
  int* ICNT = (int*)alloc(2 * N_NODES);
  int* IOFF = (int*)alloc(N_NODES + 64);
  int* ISRC = (int*)alloc(E_TOT);
  if (ws_size < cur * 4) return;
  int* IPOS = ICNT + N_NODES;

  __hip_bfloat16* x_bf = (__hip_bfloat16*)BIG1;
  __hip_bfloat16* XLR1 = (__hip_bfloat16*)XLR1f;
  __hip_bfloat16* XLR2 = (__hip_bfloat16*)BIG0;
  unsigned char* XL8 = (unsigned char*)XL8f;
  unsigned char* XL81 = (unsigned char*)XL81f;
  __hip_bfloat16* X1b = (__hip_bfloat16*)X1f;
  __hip_bfloat16* X2b = (__hip_bfloat16*)X2f;
  __hip_bfloat16* Hb  = (__hip_bfloat16*)Hbf;
  __hip_bfloat16* HNb = (__hip_bfloat16*)HNbf;
  __hip_bfloat16* WT1 = (__hip_bfloat16*)WT1f;
  __hip_bfloat16* WT2 = (__hip_bfloat16*)WT2f;
  __hip_bfloat16* WTih = (__hip_bfloat16*)WTihf;
  __hip_bfloat16* WThh = (__hip_bfloat16*)WThhf;
  __hip_bfloat16* WTh  = (__hip_bfloat16*)WThf;
  __hip_bfloat16* Tb = (__hip_bfloat16*)BIG0;

  float* o_hnew = (float*)d_out;
  float* o_res  = o_hnew + (size_t)N_NODES * 256;
  float* o_w    = o_res + (size_t)N_NODES * 2;
  float* o_ap   = o_w + (size_t)N_NODES * 2;
  float* o_ad   = o_ap + 4;

  // ---- prep ----
  prep_kernel<<<9549, 256, 0, stream>>>(c_temp, c_stereo, e_proj, f_Lt, h, eattr,
                                        bl1, br1, bl2, br2, rb1, wb1, pb1, db1,
                                        x_bf, Hb, MP, ICNT, B1, B2, BH);
  csr_count<<<(E_TOT + 255) / 256, 256, 0, stream>>>(dst, ICNT);
  csr_scan<<<1, 1024, 0, stream>>>(ICNT, IOFF, MP);
  csr_fill<<<(E_TOT + 255) / 256, 256, 0, stream>>>(src, dst, eattr, MP + 256,
                                                    IOFF, IPOS, ISRC, EAV);
  wt_all<<<1504, 256, 0, stream>>>(Wl1, Wr1, Wl2, Wr2, Wih, Whh, rW1, wW1, pW1, dW1,
                                   WT1, WT2, WTih, WThh, WTh);

  // ---- conv1 (fp8 xl + bf16 xr) ----
  mfma_gemm<6><<<dim3(4, 64), 512, 0, stream>>>(x_bf, WT1, B1, XLR1, 832, 512, XL81);
  gat_fused1<<<N_NODES / 4, 256, 0, stream>>>(XL81, XLR1, IOFF, ISRC, EAV, We1, att1, bias1, X1b);

  // ---- conv2 (fp8 xl + bf16 xr) ----
  mfma_gemm<7><<<dim3(16, 64), 512, 0, stream>>>(X1b, WT2, B2, XLR2, 256, 2048, XL8);
  gat_fused2<<<N_NODES / 4, 256, 0, stream>>>(XL8, XLR2, IOFF, ISRC, EAV, We2, att2, bias2, X2b);

  // ---- GRU (fused GEMM + elementwise) ----
  gru_gemm<<<dim3(2, 128), 512, 0, stream>>>(X2b, Hb, WTih, WThh, bih, bhh, h, o_hnew, HNb);

  // ---- heads ----
  mfma_gemm<3><<<dim3(6, 64), 512, 0, stream>>>(HNb, WTh, BH, Tb, 256, 768, nullptr);
  heads_final<<<N_NODES / 4, 256, 0, stream>>>(Tb, rW2, rb2, wW2, wb2, pW2, pb2, dW2, db2,
                                               o_res, o_w, AP, o_ad);
  ap_reduce<<<4, 256, 0, stream>>>(AP, o_ap);
}